// Round 1
// baseline (74.265 us; speedup 1.0000x reference)
//
#include <hip/hip_runtime.h>

#define OUT_H 256
#define OUT_W 192
#define HWPIX (OUT_H * OUT_W)   // 49152
#define BATCH 64

typedef float v2f __attribute__((ext_vector_type(2)));
typedef float v4f __attribute__((ext_vector_type(4)));

// ---------------- compile-time constants: Li = inv(L), cp = Li·P ----------------

constexpr double cx_ln(double x) {
  int e = 0;
  while (x >= 1.5) { x *= 0.5; ++e; }
  while (x < 0.75) { x *= 2.0; --e; }
  double t = (x - 1.0) / (x + 1.0);
  double t2 = t * t, s = 0.0, term = t;
  for (int k = 0; k < 20; ++k) { s += term / (double)(2 * k + 1); term *= t2; }
  return 2.0 * s + (double)e * 0.6931471805599453094172321214581766;
}

struct Consts {
  float li[28][25];
  float cp[2][28];
};

constexpr Consts make_consts() {
  Consts out{};
  double PX[25] = {}, PY[25] = {};
  for (int n = 0; n < 25; ++n) {
    PX[n] = -1.0 + 0.5 * (double)(n / 5);
    PY[n] = -1.0 + 0.5 * (double)(n % 5);
  }
  double M[28][56] = {};
  for (int i = 0; i < 28; ++i)
    for (int j = 0; j < 56; ++j) M[i][j] = 0.0;
  for (int i = 0; i < 25; ++i) {
    for (int j = 0; j < 25; ++j) {
      double dx = PX[i] - PX[j], dy = PY[i] - PY[j];
      double d2 = dx * dx + dy * dy;
      M[i][j] = (d2 == 0.0) ? 0.0 : d2 * cx_ln(d2);
    }
    M[i][25] = 1.0; M[i][26] = PX[i]; M[i][27] = PY[i];
    M[25][i] = 1.0; M[26][i] = PX[i]; M[27][i] = PY[i];
  }
  for (int i = 0; i < 28; ++i) M[i][28 + i] = 1.0;
  for (int k = 0; k < 28; ++k) {
    int piv = k;
    double mx = M[k][k] < 0.0 ? -M[k][k] : M[k][k];
    for (int r = k + 1; r < 28; ++r) {
      double a = M[r][k] < 0.0 ? -M[r][k] : M[r][k];
      if (a > mx) { mx = a; piv = r; }
    }
    if (piv != k)
      for (int j = 0; j < 56; ++j) { double t = M[k][j]; M[k][j] = M[piv][j]; M[piv][j] = t; }
    double inv = 1.0 / M[k][k];
    for (int j = 0; j < 56; ++j) M[k][j] *= inv;
    for (int r = 0; r < 28; ++r) {
      if (r == k) continue;
      double f = M[r][k];
      if (f != 0.0)
        for (int j = 0; j < 56; ++j) M[r][j] -= f * M[k][j];
    }
  }
  for (int k = 0; k < 28; ++k)
    for (int m = 0; m < 25; ++m) out.li[k][m] = (float)M[k][28 + m];
  for (int axis = 0; axis < 2; ++axis)
    for (int k = 0; k < 28; ++k) {
      double s = 0.0;
      for (int m = 0; m < 25; ++m)
        s += (double)out.li[k][m] * (axis ? PY[m] : PX[m]);
      out.cp[axis][k] = (float)s;
    }
  return out;
}

constexpr Consts CC = make_consts();

__device__ constexpr float PXf[25] = {
  -1.f,-1.f,-1.f,-1.f,-1.f, -0.5f,-0.5f,-0.5f,-0.5f,-0.5f,
   0.f, 0.f, 0.f, 0.f, 0.f,  0.5f, 0.5f, 0.5f, 0.5f, 0.5f,
   1.f, 1.f, 1.f, 1.f, 1.f };
__device__ constexpr float PYf[25] = {
  -1.f,-0.5f,0.f,0.5f,1.f, -1.f,-0.5f,0.f,0.5f,1.f,
  -1.f,-0.5f,0.f,0.5f,1.f, -1.f,-0.5f,0.f,0.5f,1.f,
  -1.f,-0.5f,0.f,0.5f,1.f };

// U(r^2) = r^2 log(r^2); n must be a compile-time constant after unrolling
__device__ __forceinline__ float rbf_u(float gx, float gy, int n) {
  float dx = gx - PXf[n];
  float dy = gy - PYf[n];
  float d2 = dx * dx + dy * dy;
  float u = d2 * __logf(d2);
  return (d2 == 0.0f) ? 0.0f : u;   // select discards NaN from 0*(-inf)
}

// ---------------- fused kernel ----------------
// Block = 256 pixels x 16 batches; grid = 192 px-groups x 4 batch-groups
// = 768 blocks = exactly 3 blocks/CU (12 waves/CU, balanced).
// Each lane: 4 px (two coalesced pairs: 2L and 2L+128) x 4 batches.
// K-pair-outer / batch-inner loop: 4 independent broadcast ds_read_b128
// per j (56/wave total, half of previous 112) issue ahead of the U
// computation that hides their latency; 16 independent v2f acc chains.

__global__ __launch_bounds__(256) void tps_fused(const float* __restrict__ theta,
                                                 v4f* __restrict__ out4) {
  __shared__ float sth[16 * 50];       // this block's 16 batches of theta
  __shared__ float sC[16 * 56];        // [b][k][axis]: (Cx[k],Cy[k]) pairs
  const int t = threadIdx.x;
  const int pg = blockIdx.x >> 2;      // 0..191: pixel group (256 px)
  const int bg = blockIdx.x & 3;       // 0..3:   batch group (16 batches)

  // ---- phase 1: stage this group's theta (3.2 KB, coalesced float4) ----
  {
    const float4* g4 = (const float4*)theta + bg * 200;
    float4* s4 = (float4*)sth;
    if (t < 200) s4[t] = g4[t];
  }
  __syncthreads();

  // ---- phase 2: coefficients. 32 (b,axis) pairs; k-range wave-uniform ----
  {
    const int pair = t & 63;            // lanes 0..31 active per wave
    const int kg = t >> 6;              // wave id 0..3 -> k in [7kg, 7kg+7)
    if (pair < 32) {
      const int b = pair >> 1, axis = pair & 1;
      float th[25];
      const float* src = sth + b * 50 + axis * 25;
#pragma unroll
      for (int m = 0; m < 25; ++m) th[m] = src[m];
#pragma unroll
      for (int j = 0; j < 7; ++j) {
        const int k = kg * 7 + j;       // wave-uniform -> Li row via s_load
        float acc = CC.cp[axis][k];
#pragma unroll
        for (int m = 0; m < 25; ++m) acc += CC.li[k][m] * th[m];
        sC[b * 56 + k * 2 + axis] = acc;
      }
    }
  }
  __syncthreads();

  // ---- phase 3: evaluate. 4 px/lane (pairs at 2L and 2L+128), 4 batches ----
  const int lane = t & 63;
  const int wv = t >> 6;                // wave-uniform: batch quartet
  const int pA = pg * 256 + 2 * lane;   // even; a pair never crosses a row
  const int pB = pA + 128;
  const int wA = pA % OUT_W, hA = pA / OUT_W;
  const int wB = pB % OUT_W, hB = pB / OUT_W;

  // bit-identical to np.linspace(-1,1,n).astype(float32)
  float gxA0 = (float)(-1.0 + (double)wA * (2.0 / 191.0));
  float gxA1 = (wA + 1 == OUT_W - 1) ? 1.0f
             : (float)(-1.0 + (double)(wA + 1) * (2.0 / 191.0));
  float gyA  = (hA == OUT_H - 1) ? 1.0f
             : (float)(-1.0 + (double)hA * (2.0 / 255.0));
  float gxB0 = (float)(-1.0 + (double)wB * (2.0 / 191.0));
  float gxB1 = (wB + 1 == OUT_W - 1) ? 1.0f
             : (float)(-1.0 + (double)(wB + 1) * (2.0 / 191.0));
  float gyB  = (hB == OUT_H - 1) ? 1.0f
             : (float)(-1.0 + (double)hB * (2.0 / 255.0));

  const float4* cb = (const float4*)sC + (wv * 4) * 14;  // 14 float4 / batch
  v4f* opA = out4 + (size_t)(bg * 16 + wv * 4) * (HWPIX / 2) + (pg * 128 + lane);

  v2f aA0[4], aA1[4], aB0[4], aB1[4];
#pragma unroll
  for (int b = 0; b < 4; ++b) {
    aA0[b] = (v2f){0.f, 0.f}; aA1[b] = (v2f){0.f, 0.f};
    aB0[b] = (v2f){0.f, 0.f}; aB1[b] = (v2f){0.f, 0.f};
  }

#pragma unroll
  for (int j = 0; j < 14; ++j) {
    float uA00, uA01, uA10, uA11, uB00, uB01, uB10, uB11;
    if (j < 12) {
      uA00 = rbf_u(gxA0, gyA, 2 * j); uA01 = rbf_u(gxA0, gyA, 2 * j + 1);
      uA10 = rbf_u(gxA1, gyA, 2 * j); uA11 = rbf_u(gxA1, gyA, 2 * j + 1);
      uB00 = rbf_u(gxB0, gyB, 2 * j); uB01 = rbf_u(gxB0, gyB, 2 * j + 1);
      uB10 = rbf_u(gxB1, gyB, 2 * j); uB11 = rbf_u(gxB1, gyB, 2 * j + 1);
    } else if (j == 12) {              // k=24 (last rbf), k=25 (const 1)
      uA00 = rbf_u(gxA0, gyA, 24); uA01 = 1.0f;
      uA10 = rbf_u(gxA1, gyA, 24); uA11 = 1.0f;
      uB00 = rbf_u(gxB0, gyB, 24); uB01 = 1.0f;
      uB10 = rbf_u(gxB1, gyB, 24); uB11 = 1.0f;
    } else {                           // k=26 (gx), k=27 (gy)
      uA00 = gxA0; uA01 = gyA;  uA10 = gxA1; uA11 = gyA;
      uB00 = gxB0; uB01 = gyB;  uB10 = gxB1; uB11 = gyB;
    }
#pragma unroll
    for (int b = 0; b < 4; ++b) {
      float4 c = cb[b * 14 + j];       // wave-uniform -> ds_read_b128 broadcast
      v2f c01 = {c.x, c.y};            // (Cx[2j],  Cy[2j])
      v2f c23 = {c.z, c.w};            // (Cx[2j+1],Cy[2j+1])
      v2f vA00 = {uA00, uA00}, vA01 = {uA01, uA01};
      v2f vA10 = {uA10, uA10}, vA11 = {uA11, uA11};
      v2f vB00 = {uB00, uB00}, vB01 = {uB01, uB01};
      v2f vB10 = {uB10, uB10}, vB11 = {uB11, uB11};
      aA0[b] = __builtin_elementwise_fma(vA00, c01, aA0[b]);
      aA0[b] = __builtin_elementwise_fma(vA01, c23, aA0[b]);
      aA1[b] = __builtin_elementwise_fma(vA10, c01, aA1[b]);
      aA1[b] = __builtin_elementwise_fma(vA11, c23, aA1[b]);
      aB0[b] = __builtin_elementwise_fma(vB00, c01, aB0[b]);
      aB0[b] = __builtin_elementwise_fma(vB01, c23, aB0[b]);
      aB1[b] = __builtin_elementwise_fma(vB10, c01, aB1[b]);
      aB1[b] = __builtin_elementwise_fma(vB11, c23, aB1[b]);
    }
  }

#pragma unroll
  for (int b = 0; b < 4; ++b) {
    v4f rA = {aA0[b].x, aA0[b].y, aA1[b].x, aA1[b].y};
    __builtin_nontemporal_store(rA, opA + (size_t)b * (HWPIX / 2));
    v4f rB = {aB0[b].x, aB0[b].y, aB1[b].x, aB1[b].y};
    __builtin_nontemporal_store(rB, opA + 64 + (size_t)b * (HWPIX / 2));
  }
}

// ---------------- launch ----------------

extern "C" void kernel_launch(void* const* d_in, const int* in_sizes, int n_in,
                              void* d_out, int out_size, void* d_ws, size_t ws_size,
                              hipStream_t stream) {
  const float* theta = (const float*)d_in[0];
  v4f* out4 = (v4f*)d_out;
  hipLaunchKernelGGL(tps_fused, dim3(768), dim3(256), 0, stream, theta, out4);
}